// Round 6
// baseline (120.811 us; speedup 1.0000x reference)
//
#include <hip/hip_runtime.h>

#define ROWS 1024
#define PTS 6144              // points per batch row (2048*3)
#define NDIH 6141             // dihedrals per row
#define ROWF 18432            // floats per row
#define TPR 1536              // threads per row, 4 dihedrals each (1536*4 = 6144 >= 6141)
#define THREADS 256
#define NCHUNK 6              // TPR / THREADS
#define ANG_PER_ROW 12282     // 2 * NDIH
#define EPS_SHIFT 1e-8f

typedef float vfloat4 __attribute__((ext_vector_type(4)));   // native vector for NT builtins

__global__ __launch_bounds__(THREADS) void dih_kernel(const float* __restrict__ in,
                                                      float* __restrict__ out) {
    const int b     = blockIdx.x / NCHUNK;
    const int chunk = blockIdx.x % NCHUNK;
    const int T     = chunk * THREADS + threadIdx.x;   // 0..1535 within the row
    const float* row = in + (size_t)b * ROWF;

    // first_three output (x[:, :3, :]) — once per row
    if (chunk == 0 && threadIdx.x < 9) {
        __builtin_nontemporal_store(row[threadIdx.x],
            out + (size_t)ROWS * ANG_PER_ROW + (size_t)b * 9 + threadIdx.x);
    }

    // ---- direct global window load: floats 12T .. 12T+23 (16B-aligned base) ----
    // full threads (T <= 1534): 12T+23 <= 18431 — in-bounds, 6x float4
    // tail thread (T == 1535): only dihedral 6140 valid, reads 3x float4
    const bool full = (T < TPR - 1);
    const vfloat4* g4 = (const vfloat4*)(row + 12 * T);
    float w[24];
    {
        const vfloat4 v0 = g4[0], v1 = g4[1], v2 = g4[2];
        w[0]=v0.x;  w[1]=v0.y;  w[2]=v0.z;  w[3]=v0.w;
        w[4]=v1.x;  w[5]=v1.y;  w[6]=v1.z;  w[7]=v1.w;
        w[8]=v2.x;  w[9]=v2.y;  w[10]=v2.z; w[11]=v2.w;
        if (full) {
            const vfloat4 v3 = g4[3], v4 = g4[4], v5 = g4[5];
            w[12]=v3.x; w[13]=v3.y; w[14]=v3.z; w[15]=v3.w;
            w[16]=v4.x; w[17]=v4.y; w[18]=v4.z; w[19]=v4.w;
            w[20]=v5.x; w[21]=v5.y; w[22]=v5.z; w[23]=v5.w;
        } else {
            #pragma unroll
            for (int k = 12; k < 24; ++k) w[k] = 0.0f;
        }
    }

    // ---- shared edge differences e_j = x_j - x_{j+1}, j = 0..5 ----
    float ex[6], ey[6], ez[6];
    #pragma unroll
    for (int j = 0; j < 6; ++j) {
        ex[j] = w[3*j + 0] - w[3*j + 3];
        ey[j] = w[3*j + 1] - w[3*j + 4];
        ez[j] = w[3*j + 2] - w[3*j + 5];
    }

    float sv[4], cv[4];
    #pragma unroll
    for (int k = 0; k < 4; ++k) {
        // a-b = e[k], b-c = e[k+1], c-d = e[k+2]
        const float brx = ex[k+1] + EPS_SHIFT;
        const float bry = ey[k+1] + EPS_SHIFT;
        const float brz = ez[k+1] + EPS_SHIFT;
        const float nrm2 = brx*brx + bry*bry + brz*brz;
        const float inv = rsqrtf(fmaxf(nrm2, 1e-24f));   // 1/clip(|bc|,1e-12)
        const float ux = brx * inv, uy = bry * inv, uz = brz * inv;

        // n1 = cross(a-b, u)
        const float n1x = ey[k]*uz - ez[k]*uy;
        const float n1y = ez[k]*ux - ex[k]*uz;
        const float n1z = ex[k]*uy - ey[k]*ux;
        // n2 = cross(u, c-d)
        const float n2x = uy*ez[k+2] - uz*ey[k+2];
        const float n2y = uz*ex[k+2] - ux*ez[k+2];
        const float n2z = ux*ey[k+2] - uy*ex[k+2];

        const float xc = n1x*n2x + n1y*n2y + n1z*n2z;
        // m = cross(n1, u)
        const float mx = n1y*uz - n1z*uy;
        const float my = n1z*ux - n1x*uz;
        const float mz = n1x*uy - n1y*ux;
        const float yc = mx*n2x + my*n2y + mz*n2z;

        const float xz = xc + EPS_SHIFT;
        const float r2 = yc*yc + xz*xz;
        const float rinv = rsqrtf(fmaxf(r2, 1e-30f));
        sv[k] = (r2 > 0.0f) ? yc * rinv : 0.0f;
        cv[k] = (r2 > 0.0f) ? xz * rinv : 1.0f;
    }

    // ---- nontemporal stores (don't evict L3-resident input) ----
    const int i = 4 * T;
    const size_t obase = (size_t)b * ANG_PER_ROW;
    if (full) {
        // sin: obase even, i multiple of 4 -> 16B-aligned vfloat4
        vfloat4 sv4;
        sv4.x = sv[0]; sv4.y = sv[1]; sv4.z = sv[2]; sv4.w = sv[3];
        __builtin_nontemporal_store(sv4, (vfloat4*)(out + obase + i));
        // cos block base odd (NDIH=6141) -> scalar stores
        float* co = out + obase + NDIH + i;
        __builtin_nontemporal_store(cv[0], co + 0);
        __builtin_nontemporal_store(cv[1], co + 1);
        __builtin_nontemporal_store(cv[2], co + 2);
        __builtin_nontemporal_store(cv[3], co + 3);
    } else {
        // tail thread: only dihedral i = 6140
        __builtin_nontemporal_store(sv[0], out + obase + i);
        __builtin_nontemporal_store(cv[0], out + obase + NDIH + i);
    }
}

extern "C" void kernel_launch(void* const* d_in, const int* in_sizes, int n_in,
                              void* d_out, int out_size, void* d_ws, size_t ws_size,
                              hipStream_t stream) {
    const float* in = (const float*)d_in[0];
    float* out = (float*)d_out;
    dih_kernel<<<dim3(ROWS * NCHUNK), dim3(THREADS), 0, stream>>>(in, out);
}